// Round 4
// baseline (2451.613 us; speedup 1.0000x reference)
//
#include <hip/hip_runtime.h>

#define MM 8192
#define KK 4096
#define NN 11008
#define BK 32
#define NT (KK / BK)   // 128 K-steps

typedef __attribute__((ext_vector_type(8))) __bf16 bf16x8;
typedef __attribute__((ext_vector_type(4))) float f32x4;
typedef __attribute__((ext_vector_type(4))) int   i32x4;

// Split two f32 into packed bf16 hi parts (RTZ: top 16 bits) and bf16 lo parts
// (bf16 of the exact residual). hi: [bf16(f0) | bf16(f1)] in one u32 via v_perm.
__device__ __forceinline__ uint2 split2(float f0, float f1) {
  unsigned u0 = __float_as_uint(f0), u1 = __float_as_uint(f1);
  unsigned hi = __builtin_amdgcn_perm(u1, u0, 0x07060302u);
  float l0 = f0 - __uint_as_float(u0 & 0xFFFF0000u);   // exact residual
  float l1 = f1 - __uint_as_float(u1 & 0xFFFF0000u);
  unsigned lo = __builtin_amdgcn_perm(__float_as_uint(l1), __float_as_uint(l0), 0x07060302u);
  return make_uint2(hi, lo);
}

// LDS row layout: 128 bytes per row = [32 hi bf16 | 32 lo bf16], swizzled:
// addr(row, off) = row*128 + (off ^ ((row&7)<<4)); lo addr = hi addr ^ 64.
// Write slot (tid&3)^(srow&7) and read slot (lane>>4)^(frow&7) use the same
// involution -> consistent, bijective, zero extra bank conflict.

__global__ __launch_bounds__(256, 2) void dq_gemm_kernel(
    const float* __restrict__ X, const float* __restrict__ W,
    const float* __restrict__ S, float* __restrict__ Y) {
  __shared__ __align__(16) unsigned char sA[128 * 128];  // 16 KiB
  __shared__ __align__(16) unsigned char sB[128 * 128];  // 16 KiB

  const int tid  = (int)threadIdx.x;
  const int lane = tid & 63;
  const int wid  = tid >> 6;

  // ---- grid mapping: XCD-bijective swizzle (5504 = 8*688), then 8-m-tile groups
  int pid = (int)blockIdx.x;
  int sp  = (pid & 7) * 688 + (pid >> 3);   // XCD x owns contiguous sp range
  int grp = sp / 688;                        // 0..7  (one group per XCD)
  int rem = sp % 688;
  int tm  = grp * 8 + (rem & 7);             // 0..63
  int tn  = rem >> 3;                        // 0..85
  const int m0 = tm * 128, n0 = tn * 128;

  // ---- staging assignment: thread covers rows {srow, srow+64}, 8 k each
  const int srow = tid >> 2;                 // 0..63
  const int skof = (tid & 3) << 3;           // k offset in floats: 0,8,16,24
  const size_t RSTRIDE = (size_t)64 * KK;    // 64-row jump, SGPR-resident
  const float* aptr = X + (size_t)(m0 + srow) * KK + skof;
  const float* bptr = W + (size_t)(n0 + srow) * KK + skof;
  const float* sp0  = S + (size_t)((n0 + srow) >> 6) * 64;        // scale row for srow
  const float* sp1  = S + (size_t)((n0 + srow + 64) >> 6) * 64;   // scale row for srow+64
  const int wo0 = srow * 128 + ((((tid & 3) << 4)) ^ ((srow & 7) << 4));
  const int wo1 = wo0 + 64 * 128;            // (srow+64)&7 == srow&7

  // ---- fragment read offsets (16x16x32: lane holds A[l&15][(l>>4)*8 + j])
  const int wr   = wid >> 1, wc = wid & 1;
  const int frow = lane & 15;
  const int fko  = (lane >> 4) << 4;         // byte offset of the 8-k run
  const int roA  = (wr * 64 + frow) * 128 + (fko ^ ((frow & 7) << 4));
  const int roB  = (wc * 64 + frow) * 128 + (fko ^ ((frow & 7) << 4));

  float4 ra0, ra1, ra2, ra3, rb0, rb1, rb2, rb3;
  float  sc0, sc1;
  i32x4  hA0, lA0, hA1, lA1, hB0, lB0, hB1, lB1;

#define LOADT(kt_) do {                                                  \
    const float* pa_ = aptr + (kt_) * BK;                                \
    const float* pb_ = bptr + (kt_) * BK;                                \
    ra0 = *(const float4*)(pa_);                                         \
    ra1 = *(const float4*)(pa_ + 4);                                     \
    ra2 = *(const float4*)(pa_ + RSTRIDE);                               \
    ra3 = *(const float4*)(pa_ + RSTRIDE + 4);                           \
    rb0 = *(const float4*)(pb_);                                         \
    rb1 = *(const float4*)(pb_ + 4);                                     \
    rb2 = *(const float4*)(pb_ + RSTRIDE);                               \
    rb3 = *(const float4*)(pb_ + RSTRIDE + 4);                           \
    sc0 = sp0[(kt_) >> 1];                                               \
    sc1 = sp1[(kt_) >> 1];                                               \
  } while (0)

#define CVTT() do {                                                      \
    uint2 t_;                                                            \
    t_ = split2(ra0.x, ra0.y);           hA0.x = t_.x; lA0.x = t_.y;     \
    t_ = split2(ra0.z, ra0.w);           hA0.y = t_.x; lA0.y = t_.y;     \
    t_ = split2(ra1.x, ra1.y);           hA0.z = t_.x; lA0.z = t_.y;     \
    t_ = split2(ra1.z, ra1.w);           hA0.w = t_.x; lA0.w = t_.y;     \
    t_ = split2(ra2.x, ra2.y);           hA1.x = t_.x; lA1.x = t_.y;     \
    t_ = split2(ra2.z, ra2.w);           hA1.y = t_.x; lA1.y = t_.y;     \
    t_ = split2(ra3.x, ra3.y);           hA1.z = t_.x; lA1.z = t_.y;     \
    t_ = split2(ra3.z, ra3.w);           hA1.w = t_.x; lA1.w = t_.y;     \
    t_ = split2(rb0.x * sc0, rb0.y * sc0); hB0.x = t_.x; lB0.x = t_.y;   \
    t_ = split2(rb0.z * sc0, rb0.w * sc0); hB0.y = t_.x; lB0.y = t_.y;   \
    t_ = split2(rb1.x * sc0, rb1.y * sc0); hB0.z = t_.x; lB0.z = t_.y;   \
    t_ = split2(rb1.z * sc0, rb1.w * sc0); hB0.w = t_.x; lB0.w = t_.y;   \
    t_ = split2(rb2.x * sc1, rb2.y * sc1); hB1.x = t_.x; lB1.x = t_.y;   \
    t_ = split2(rb2.z * sc1, rb2.w * sc1); hB1.y = t_.x; lB1.y = t_.y;   \
    t_ = split2(rb3.x * sc1, rb3.y * sc1); hB1.z = t_.x; lB1.z = t_.y;   \
    t_ = split2(rb3.z * sc1, rb3.w * sc1); hB1.w = t_.x; lB1.w = t_.y;   \
  } while (0)

  f32x4 acc[4][4];
  const f32x4 z4 = {0.f, 0.f, 0.f, 0.f};
#pragma unroll
  for (int m = 0; m < 4; ++m)
#pragma unroll
    for (int n = 0; n < 4; ++n) acc[m][n] = z4;

  LOADT(0);
  CVTT();

  for (int kt = 0; kt < NT; ++kt) {
    __syncthreads();                       // previous compute done reading LDS
    *(i32x4*)&sA[wo0]       = hA0;
    *(i32x4*)&sA[wo0 ^ 64]  = lA0;
    *(i32x4*)&sA[wo1]       = hA1;
    *(i32x4*)&sA[wo1 ^ 64]  = lA1;
    *(i32x4*)&sB[wo0]       = hB0;
    *(i32x4*)&sB[wo0 ^ 64]  = lB0;
    *(i32x4*)&sB[wo1]       = hB1;
    *(i32x4*)&sB[wo1 ^ 64]  = lB1;
    __syncthreads();                       // tile visible

    if (kt + 1 < NT) LOADT(kt + 1);        // issue next-tile loads early (hide HBM)

    bf16x8 ah[4], al[4], bh[4], bl[4];
#pragma unroll
    for (int m = 0; m < 4; ++m) {
      ah[m] = *(const bf16x8*)&sA[roA + m * 2048];
      al[m] = *(const bf16x8*)&sA[(roA + m * 2048) ^ 64];
      bh[m] = *(const bf16x8*)&sB[roB + m * 2048];
      bl[m] = *(const bf16x8*)&sB[(roB + m * 2048) ^ 64];
    }
#pragma unroll
    for (int m = 0; m < 4; ++m)
#pragma unroll
      for (int n = 0; n < 4; ++n) {
        acc[m][n] = __builtin_amdgcn_mfma_f32_16x16x32_bf16(ah[m], bh[n], acc[m][n], 0, 0, 0);
        acc[m][n] = __builtin_amdgcn_mfma_f32_16x16x32_bf16(al[m], bh[n], acc[m][n], 0, 0, 0);
        acc[m][n] = __builtin_amdgcn_mfma_f32_16x16x32_bf16(ah[m], bl[n], acc[m][n], 0, 0, 0);
      }

    if (kt + 1 < NT) CVTT();               // convert after MFMAs (loads have landed)
  }

  // ---- epilogue: C/D layout col=lane&15, row=(lane>>4)*4+reg (m89-verified)
  const size_t orow0 = (size_t)m0 + (size_t)(wr * 64) + (size_t)((lane >> 4) << 2);
  const int    ocol0 = n0 + wc * 64 + frow;
#pragma unroll
  for (int m = 0; m < 4; ++m)
#pragma unroll
    for (int r = 0; r < 4; ++r) {
      float* yp = Y + (orow0 + m * 16 + r) * (size_t)NN + ocol0;
#pragma unroll
      for (int n = 0; n < 4; ++n) yp[n * 16] = acc[m][n][r];
    }
#undef LOADT
#undef CVTT
}

extern "C" void kernel_launch(void* const* d_in, const int* in_sizes, int n_in,
                              void* d_out, int out_size, void* d_ws, size_t ws_size,
                              hipStream_t stream) {
  const float* X = (const float*)d_in[0];   // (8192, 4096)
  const float* W = (const float*)d_in[1];   // (11008, 4096)
  const float* S = (const float*)d_in[2];   // (172, 64)
  float* Y = (float*)d_out;                 // (8192, 11008)
  const int nwg = (MM / 128) * (NN / 128);  // 64 * 86 = 5504
  dq_gemm_kernel<<<nwg, 256, 0, stream>>>(X, W, S, Y);
}